// Round 9
// baseline (231.164 us; speedup 1.0000x reference)
//
#include <hip/hip_runtime.h>
#include <hip/hip_bf16.h>

// GCN 2-layer encoder, MI355X (gfx950).
// Known: float tensors bf16, edge_index int64 (self-detection kept).
// Round 9: agg kernels restructured — 4 lanes/node (16B/lane 64B row-slice),
// 16 nodes/wave, unroll-4 => 64 loads in flight/wave, no shfl reduce, no
// per-node drain; XCD feature-slicing (slice=(bid%8)>>1) so each XCD's L2
// holds a 3.2MB table slice. 7 dispatches.
// Pipeline:
//   k_prep_w: Bsw1/Bsw2 (MFMA B-frag order) + b1c/b2c + flags
//   k_edges -> k_bsort(+scan +prescale xs=dinv*x): CSR/offsets/dinv/xs
//   a1[v] = dinv[v]*(xs[v] + sum xs[csr])      [sliced gather]
//   h2s = (relu(a1@W1+b1) @ W2) * dinv[row]     [fused MFMA, LDS h1]
//   out[v] = dinv[v]*(h2s[v] + sum h2s[csr]) + b2   [sliced gather]

typedef __bf16 bf16x8v __attribute__((ext_vector_type(8)));
typedef short  s16x8   __attribute__((ext_vector_type(8)));
typedef float  f32x4   __attribute__((ext_vector_type(4)));

#define IN_DIM 128
#define HID    256
#define OUTD   128
#define BKT_SHIFT 7
#define BKT_NODES 128
#define MAXB 512            // max buckets (N <= 65536)
#define CAP  8192           // per-bucket capacity (mean 2046, 40+ sigma margin)
#define EBLK 512            // k_edges grid

__device__ __forceinline__ float2 bf2f(__hip_bfloat162 v) {
    return make_float2(__bfloat162float(v.x), __bfloat162float(v.y));
}
__device__ __forceinline__ __hip_bfloat162 f2bf(float a, float b) {
    __hip_bfloat162 r; r.x = __float2bfloat16(a); r.y = __float2bfloat16(b); return r;
}
__device__ __forceinline__ void acc_row(float* acc, s16x8 r) {
    __hip_bfloat162* p = (__hip_bfloat162*)&r;
#pragma unroll
    for (int j = 0; j < 4; ++j) {
        float2 f = bf2f(p[j]);
        acc[2 * j]     += f.x;
        acc[2 * j + 1] += f.y;
    }
}

// per-block dtype self-detection (W2 uniform +-1/16: any bf16-exp >= 0x7F => fp32)
__device__ __forceinline__ int detect_f32(const void* W2raw) {
    const unsigned short* u = (const unsigned short*)W2raw;
    int f32 = 0;
#pragma unroll
    for (int i = 0; i < 64; ++i) {
        unsigned e = (u[i] >> 7) & 0xFF;
        if (e >= 0x7F) f32 = 1;
    }
    return f32;
}

// ---------------- fused weight prep (+flags) ----------------
// Bsw[(nt*KC+kc)*64 + lane][j] = W[kc*32 + (lane>>4)*8 + j][nt*16 + (lane&15)]

__device__ __forceinline__ short ldw(const void* raw, int idx, int f32) {
    if (f32) {
        __hip_bfloat16 h = __float2bfloat16(((const float*)raw)[idx]);
        return *(short*)&h;
    }
    return ((const short*)raw)[idx];
}

template <int K, int NN>
__device__ __forceinline__ void swz_one(const void* Wraw, int f32,
                                        short* __restrict__ Bsw, int tid) {
    constexpr int KC = K / 32;
    constexpr int NT = NN / 16;
    if (tid >= NT * KC * 64) return;
    int lane = tid & 63;
    int kc   = (tid >> 6) % KC;
    int nt   = tid / (64 * KC);
    int n  = nt * 16 + (lane & 15);
    int kb = kc * 32 + (lane >> 4) * 8;
    s16x8 v;
#pragma unroll
    for (int j = 0; j < 8; ++j) v[j] = ldw(Wraw, (kb + j) * NN + n, f32);
    ((s16x8*)Bsw)[tid] = v;
}

__global__ __launch_bounds__(256) void k_prep_w(
        const void* W1raw, const void* b1raw, const void* W2raw, const void* b2raw,
        const void* eiraw, short* __restrict__ Bsw1, short* __restrict__ Bsw2,
        __hip_bfloat16* __restrict__ b1c, __hip_bfloat16* __restrict__ b2c,
        int* __restrict__ flags) {
    int f32 = detect_f32(W2raw);
    int blk = blockIdx.x, t = threadIdx.x;
    if (blk < 16) {
        swz_one<IN_DIM, HID>(W1raw, f32, Bsw1, blk * 256 + t);
    } else if (blk < 32) {
        swz_one<HID, OUTD>(W2raw, f32, Bsw2, (blk - 16) * 256 + t);
    } else {
        short s1 = ldw(b1raw, t, f32);
        b1c[t] = *(__hip_bfloat16*)&s1;
        if (t < OUTD) {
            short s2 = ldw(b2raw, t, f32);
            b2c[t] = *(__hip_bfloat16*)&s2;
        }
        if (t == 0) {
            const unsigned* ip = (const unsigned*)eiraw;
            unsigned orodd = 0;
#pragma unroll
            for (int i = 0; i < 64; ++i) orodd |= ip[2 * i + 1];
            flags[0] = f32;
            flags[1] = (orodd == 0) ? 1 : 0;   // int64 upper words all zero
        }
    }
}

// ---------------- one-pass edge bucketing (wave-privatized) ----------------

__global__ __launch_bounds__(256) void k_edges(
        const void* __restrict__ ei_, int E, int N, int NB,
        const int* __restrict__ flags, int* __restrict__ bcnt,
        unsigned* __restrict__ ppack) {
    __shared__ int lhist[4][MAXB];
    __shared__ int lbase[4][MAXB];
    int wv = threadIdx.x >> 6;
    int i64 = flags[1];
    const long long* p64 = (const long long*)ei_;
    const int*       p32 = (const int*)ei_;
    int per = (E + gridDim.x - 1) / gridDim.x;
    int e0 = blockIdx.x * per, e1 = min(e0 + per, E);
    for (int i = threadIdx.x; i < NB; i += 256) {
        lhist[0][i] = 0; lhist[1][i] = 0; lhist[2][i] = 0; lhist[3][i] = 0;
    }
    __syncthreads();
    for (int e = e0 + threadIdx.x; e < e1; e += 256) {
        int d = i64 ? (int)p64[E + e] : p32[E + e];
        if ((unsigned)d >= (unsigned)N) d = 0;
        atomicAdd(&lhist[wv][((unsigned)d) >> BKT_SHIFT], 1);
    }
    __syncthreads();
    for (int i = threadIdx.x; i < NB; i += 256) {
        int c0 = lhist[0][i], c1 = lhist[1][i], c2 = lhist[2][i], c3 = lhist[3][i];
        int tot = c0 + c1 + c2 + c3;
        int g = tot ? atomicAdd(&bcnt[i], tot) : 0;
        lbase[0][i] = g;
        lbase[1][i] = g + c0;
        lbase[2][i] = g + c0 + c1;
        lbase[3][i] = g + c0 + c1 + c2;
        lhist[0][i] = 0; lhist[1][i] = 0; lhist[2][i] = 0; lhist[3][i] = 0;
    }
    __syncthreads();
    for (int e = e0 + threadIdx.x; e < e1; e += 256) {
        int d = i64 ? (int)p64[E + e] : p32[E + e];
        int s = i64 ? (int)p64[e]     : p32[e];
        if ((unsigned)d >= (unsigned)N) d = 0;
        if ((unsigned)s >= (unsigned)N) s = 0;
        int b = ((unsigned)d) >> BKT_SHIFT;
        int pos = lbase[wv][b] + atomicAdd(&lhist[wv][b], 1);
        if (pos < CAP)
            ppack[(size_t)b * CAP + pos] = ((unsigned)(d & (BKT_NODES - 1)) << 25) | (unsigned)s;
    }
}

// ---------------- bucket sort (+bucket scan, +prescale xs) ----------------

__global__ __launch_bounds__(512) void k_bsort(const int* __restrict__ bcnt,
                                               const unsigned* __restrict__ ppack,
                                               int NB,
                                               int* __restrict__ csr, int* __restrict__ offsets,
                                               float* __restrict__ dinv, int N,
                                               const void* __restrict__ xraw,
                                               const int* __restrict__ flags,
                                               __hip_bfloat16* __restrict__ xs) {
    __shared__ int sb[MAXB];
    __shared__ int h[BKT_NODES], base[BKT_NODES], s[BKT_NODES];
    __shared__ float sdv[BKT_NODES];
    int b = blockIdx.x;
    int t = threadIdx.x;
    int c = (t < NB) ? min(bcnt[t], CAP) : 0;
    sb[t] = c;
    __syncthreads();
    for (int off = 1; off < MAXB; off <<= 1) {
        int u = (t >= off) ? sb[t - off] : 0;
        __syncthreads();
        sb[t] += u;
        __syncthreads();
    }
    int cnt   = min(bcnt[b], CAP);
    int ebase = sb[b] - cnt;
    if (b == NB - 1 && t == 0) offsets[N] = sb[b];
    const unsigned* pp = ppack + (size_t)b * CAP;
    if (t < BKT_NODES) h[t] = 0;
    __syncthreads();
    for (int e = t; e < cnt; e += 512) atomicAdd(&h[pp[e] >> 25], 1);
    __syncthreads();
    int v = (t < BKT_NODES) ? h[t] : 0;
    if (t < BKT_NODES) s[t] = v;
    __syncthreads();
    for (int off = 1; off < BKT_NODES; off <<= 1) {
        int u = (t < BKT_NODES && t >= off) ? s[t - off] : 0;
        __syncthreads();
        if (t < BKT_NODES) s[t] += u;
        __syncthreads();
    }
    if (t < BKT_NODES) {
        int excl = s[t] - v;
        base[t] = excl;
        int node = b * BKT_NODES + t;
        float dv = 0.f;
        if (node < N) {
            dv = rsqrtf((float)(v + 1));
            offsets[node] = ebase + excl;
            dinv[node] = dv;
        } else {
            dinv[node] = 0.f;
        }
        sdv[t] = dv;
        h[t] = 0;
    }
    __syncthreads();
    for (int e = t; e < cnt; e += 512) {
        unsigned pk = pp[e];
        int ld = pk >> 25;
        int pos = ebase + base[ld] + atomicAdd(&h[ld], 1);
        csr[pos] = (int)(pk & 0x1FFFFFFu);
    }
    // fused prescale: xs rows [b*128, b*128+128) = dinv * x
    int f32 = flags[0];
    if (!f32) {
        const s16x8* xg = (const s16x8*)xraw;
        s16x8* xo = (s16x8*)xs;
        for (int u = t; u < BKT_NODES * 16; u += 512) {
            int row = u >> 4;
            int node = b * BKT_NODES + row;
            float dv = sdv[row];
            s16x8 val = {0, 0, 0, 0, 0, 0, 0, 0};
            if (node < N) {
                s16x8 xin = xg[(size_t)node * 16 + (u & 15)];
                __hip_bfloat162* xp = (__hip_bfloat162*)&xin;
                __hip_bfloat162* vp = (__hip_bfloat162*)&val;
#pragma unroll
                for (int j = 0; j < 4; ++j) {
                    float2 f = bf2f(xp[j]);
                    vp[j] = f2bf(dv * f.x, dv * f.y);
                }
            }
            xo[(size_t)node * 16 + (u & 15)] = val;
        }
    } else {
        const float4* xg = (const float4*)xraw;
        __hip_bfloat162* xo = (__hip_bfloat162*)xs;
        for (int u = t; u < BKT_NODES * 32; u += 512) {
            int row = u >> 5;
            int node = b * BKT_NODES + row;
            float dv = sdv[row];
            __hip_bfloat162 v0 = f2bf(0.f, 0.f), v1 = v0;
            if (node < N) {
                float4 xin = xg[(size_t)node * 32 + (u & 31)];
                v0 = f2bf(dv * xin.x, dv * xin.y);
                v1 = f2bf(dv * xin.z, dv * xin.w);
            }
            xo[(size_t)node * 64 + (u & 31) * 2]     = v0;
            xo[(size_t)node * 64 + (u & 31) * 2 + 1] = v1;
        }
    }
}

// ---------------- sliced gather aggregation ----------------
// grid = (Npad/64)*4 blocks. slice = (bid%8)>>1 (XCD-locality heuristic:
// each XCD sees one 64B feature slice -> 3.2MB table slice fits 4MB L2).
// nb = (bid>>3)*2 + (bid&1). Wave handles 16 nodes; 4 lanes per node load
// 16B each (one 64B row-slice); unroll 4 -> 64 loads in flight per wave;
// no cross-lane reduction (each lane owns its 8 features).

__global__ __launch_bounds__(256) void k_agg1(
        const s16x8* __restrict__ xs8, const int* __restrict__ offsets,
        const int* __restrict__ csr, const float* __restrict__ dinv,
        s16x8* __restrict__ a8, int N, int Npad) {
    int bid = blockIdx.x;
    int slice = (bid & 7) >> 1;
    int nb = ((bid >> 3) << 1) | (bid & 1);
    int wave = threadIdx.x >> 6, lane = threadIdx.x & 63;
    int sg = lane >> 2, lg = lane & 3;
    int v  = nb * 64 + wave * 16 + sg;
    int su = slice * 4 + lg;                 // 16B unit within 256B row
    if (v >= Npad) return;
    if (v >= N) {
        s16x8 z = {0, 0, 0, 0, 0, 0, 0, 0};
        a8[(size_t)v * 16 + su] = z;
        return;
    }
    float acc[8];
    acc_row_init:;
    {
        s16x8 self = xs8[(size_t)v * 16 + su];
        __hip_bfloat162* p = (__hip_bfloat162*)&self;
#pragma unroll
        for (int j = 0; j < 4; ++j) {
            float2 f = bf2f(p[j]);
            acc[2 * j] = f.x; acc[2 * j + 1] = f.y;
        }
    }
    int e = offsets[v], o1 = offsets[v + 1];
    for (; e + 3 < o1; e += 4) {
        int s0 = csr[e], s1 = csr[e + 1], s2 = csr[e + 2], s3 = csr[e + 3];
        s16x8 r0 = xs8[(size_t)s0 * 16 + su];
        s16x8 r1 = xs8[(size_t)s1 * 16 + su];
        s16x8 r2 = xs8[(size_t)s2 * 16 + su];
        s16x8 r3 = xs8[(size_t)s3 * 16 + su];
        acc_row(acc, r0); acc_row(acc, r1); acc_row(acc, r2); acc_row(acc, r3);
    }
    for (; e < o1; ++e) acc_row(acc, xs8[(size_t)csr[e] * 16 + su]);
    float dv = dinv[v];
    s16x8 outv;
    __hip_bfloat162* op = (__hip_bfloat162*)&outv;
#pragma unroll
    for (int j = 0; j < 4; ++j) op[j] = f2bf(dv * acc[2 * j], dv * acc[2 * j + 1]);
    a8[(size_t)v * 16 + su] = outv;
}

__global__ __launch_bounds__(256) void k_agg2(
        const s16x8* __restrict__ h8, const int* __restrict__ offsets,
        const int* __restrict__ csr, const float* __restrict__ dinv,
        const __hip_bfloat16* __restrict__ b2c, const int* __restrict__ flags,
        void* __restrict__ outraw, int N, int Npad) {
    int bid = blockIdx.x;
    int slice = (bid & 7) >> 1;
    int nb = ((bid >> 3) << 1) | (bid & 1);
    int wave = threadIdx.x >> 6, lane = threadIdx.x & 63;
    int sg = lane >> 2, lg = lane & 3;
    int v  = nb * 64 + wave * 16 + sg;
    int su = slice * 4 + lg;
    if (v >= N) return;
    float acc[8];
    {
        s16x8 self = h8[(size_t)v * 16 + su];
        __hip_bfloat162* p = (__hip_bfloat162*)&self;
#pragma unroll
        for (int j = 0; j < 4; ++j) {
            float2 f = bf2f(p[j]);
            acc[2 * j] = f.x; acc[2 * j + 1] = f.y;
        }
    }
    int e = offsets[v], o1 = offsets[v + 1];
    for (; e + 3 < o1; e += 4) {
        int s0 = csr[e], s1 = csr[e + 1], s2 = csr[e + 2], s3 = csr[e + 3];
        s16x8 r0 = h8[(size_t)s0 * 16 + su];
        s16x8 r1 = h8[(size_t)s1 * 16 + su];
        s16x8 r2 = h8[(size_t)s2 * 16 + su];
        s16x8 r3 = h8[(size_t)s3 * 16 + su];
        acc_row(acc, r0); acc_row(acc, r1); acc_row(acc, r2); acc_row(acc, r3);
    }
    for (; e < o1; ++e) acc_row(acc, h8[(size_t)csr[e] * 16 + su]);
    float dv = dinv[v];
    float bb[8];
    {
        s16x8 bv = ((const s16x8*)b2c)[su];
        __hip_bfloat162* bp = (__hip_bfloat162*)&bv;
#pragma unroll
        for (int j = 0; j < 4; ++j) {
            float2 f = bf2f(bp[j]);
            bb[2 * j] = f.x; bb[2 * j + 1] = f.y;
        }
    }
    if (flags[0]) {
        float4* of = (float4*)outraw;
        float4 o0v = {dv * acc[0] + bb[0], dv * acc[1] + bb[1],
                      dv * acc[2] + bb[2], dv * acc[3] + bb[3]};
        float4 o1v = {dv * acc[4] + bb[4], dv * acc[5] + bb[5],
                      dv * acc[6] + bb[6], dv * acc[7] + bb[7]};
        of[(size_t)v * 32 + su * 2]     = o0v;
        of[(size_t)v * 32 + su * 2 + 1] = o1v;
    } else {
        s16x8 outv;
        __hip_bfloat162* op = (__hip_bfloat162*)&outv;
#pragma unroll
        for (int j = 0; j < 4; ++j)
            op[j] = f2bf(dv * acc[2 * j] + bb[2 * j], dv * acc[2 * j + 1] + bb[2 * j + 1]);
        ((s16x8*)outraw)[(size_t)v * 16 + su] = outv;
    }
}

// ---------------- fused MFMA GEMM1+GEMM2 ----------------

__global__ __launch_bounds__(256) void k_gemm12(
        const __hip_bfloat16* __restrict__ A, const __hip_bfloat16* __restrict__ Bsw1,
        const __hip_bfloat16* __restrict__ b1c, const __hip_bfloat16* __restrict__ Bsw2,
        const float* __restrict__ dinv, __hip_bfloat16* __restrict__ h2s) {
    __shared__ __align__(16) __hip_bfloat16 hl[128 * HID];   // 64 KB
    int wave = threadIdx.x >> 6, lane = threadIdx.x & 63;
    int quad = lane >> 4, l16 = lane & 15;
    int mw = wave * 32;
    int gm = blockIdx.x * 128 + mw;

    bf16x8v a1f[2][4];
#pragma unroll
    for (int st = 0; st < 2; ++st)
#pragma unroll
        for (int kc = 0; kc < 4; ++kc)
            a1f[st][kc] = *reinterpret_cast<const bf16x8v*>(
                A + (size_t)(gm + st * 16 + l16) * IN_DIM + kc * 32 + quad * 8);

    const bf16x8v* B1 = reinterpret_cast<const bf16x8v*>(Bsw1);
    for (int nt = 0; nt < HID / 16; ++nt) {
        f32x4 acc0 = {0.f, 0.f, 0.f, 0.f}, acc1 = {0.f, 0.f, 0.f, 0.f};
#pragma unroll
        for (int kc = 0; kc < 4; ++kc) {
            bf16x8v bfrag = B1[(nt * 4 + kc) * 64 + lane];
            acc0 = __builtin_amdgcn_mfma_f32_16x16x32_bf16(a1f[0][kc], bfrag, acc0, 0, 0, 0);
            acc1 = __builtin_amdgcn_mfma_f32_16x16x32_bf16(a1f[1][kc], bfrag, acc1, 0, 0, 0);
        }
        int col = nt * 16 + l16;
        int gcol = col >> 3, csub = col & 7;
        float bv = __bfloat162float(b1c[col]);
#pragma unroll
        for (int r = 0; r < 4; ++r) {
            float v0 = acc0[r] + bv; v0 = v0 > 0.f ? v0 : 0.f;
            float v1 = acc1[r] + bv; v1 = v1 > 0.f ? v1 : 0.f;
            int r0 = mw + quad * 4 + r;
            int r1 = mw + 16 + quad * 4 + r;
            ((__hip_bfloat16*)((char*)hl + (size_t)r0 * (HID * 2) + ((gcol ^ (r0 & 31)) << 4)))[csub] = __float2bfloat16(v0);
            ((__hip_bfloat16*)((char*)hl + (size_t)r1 * (HID * 2) + ((gcol ^ (r1 & 31)) << 4)))[csub] = __float2bfloat16(v1);
        }
    }
    // per-wave-private rows: no __syncthreads needed

    bf16x8v a2f[2][8];
#pragma unroll
    for (int st = 0; st < 2; ++st)
#pragma unroll
        for (int kc = 0; kc < 8; ++kc) {
            int row = mw + st * 16 + l16;
            int g = (kc * 4 + quad) ^ (row & 31);
            a2f[st][kc] = *reinterpret_cast<const bf16x8v*>(
                (char*)hl + (size_t)row * (HID * 2) + ((size_t)g << 4));
        }
    const bf16x8v* B2 = reinterpret_cast<const bf16x8v*>(Bsw2);
    int rb0 = gm + quad * 4, rb1 = gm + 16 + quad * 4;
    float sc0[4], sc1[4];
#pragma unroll
    for (int r = 0; r < 4; ++r) { sc0[r] = dinv[rb0 + r]; sc1[r] = dinv[rb1 + r]; }
    for (int nt = 0; nt < OUTD / 16; ++nt) {
        f32x4 acc0 = {0.f, 0.f, 0.f, 0.f}, acc1 = {0.f, 0.f, 0.f, 0.f};
#pragma unroll
        for (int kc = 0; kc < 8; ++kc) {
            bf16x8v bfrag = B2[(nt * 8 + kc) * 64 + lane];
            acc0 = __builtin_amdgcn_mfma_f32_16x16x32_bf16(a2f[0][kc], bfrag, acc0, 0, 0, 0);
            acc1 = __builtin_amdgcn_mfma_f32_16x16x32_bf16(a2f[1][kc], bfrag, acc1, 0, 0, 0);
        }
        int col = nt * 16 + l16;
#pragma unroll
        for (int r = 0; r < 4; ++r) {
            h2s[(size_t)(rb0 + r) * OUTD + col] = __float2bfloat16(acc0[r] * sc0[r]);
            h2s[(size_t)(rb1 + r) * OUTD + col] = __float2bfloat16(acc1[r] * sc1[r]);
        }
    }
}

// ---------------- host launch ----------------

extern "C" void kernel_launch(void* const* d_in, const int* in_sizes, int n_in,
                              void* d_out, int out_size, void* d_ws, size_t ws_size,
                              hipStream_t stream) {
    const void* x  = d_in[0];
    const void* ei = d_in[1];
    const void* W1 = d_in[2];
    const void* b1 = d_in[3];
    const void* W2 = d_in[4];
    const void* b2 = d_in[5];

    const int N = in_sizes[0] / IN_DIM;       // 50000
    const int E = in_sizes[1] / 2;            // 800000
    const int Npad = ((N + 127) / 128) * 128; // 50048 (multiple of 128)
    const int NB = Npad / BKT_NODES;          // 391

    char* w = (char*)d_ws;
    auto alloc = [&](size_t bytes) -> void* {
        void* p = (void*)w;
        w += (bytes + 255) / 256 * 256;
        return p;
    };
    int*   flags   = (int*)alloc(256);
    int*   bcnt    = (int*)alloc((size_t)MAXB * 4);
    int*   offsets = (int*)alloc((size_t)(N + 1) * 4);
    float* dinv    = (float*)alloc((size_t)Npad * 4);
    unsigned* ppack = (unsigned*)alloc((size_t)NB * CAP * 4);
    int*   csr     = (int*)alloc((size_t)E * 4);
    short* Bsw1 = (short*)alloc((size_t)IN_DIM * HID * 2);
    short* Bsw2 = (short*)alloc((size_t)HID * OUTD * 2);
    __hip_bfloat16* b1c = (__hip_bfloat16*)alloc((size_t)HID * 2);
    __hip_bfloat16* b2c = (__hip_bfloat16*)alloc((size_t)OUTD * 2);
    __hip_bfloat16* xs  = (__hip_bfloat16*)alloc((size_t)Npad * IN_DIM * 2);
    __hip_bfloat16* a1  = (__hip_bfloat16*)alloc((size_t)Npad * IN_DIM * 2);
    __hip_bfloat16* h2s = xs;   // xs dead after agg1; reuse for gemm12 output

    k_prep_w<<<33, 256, 0, stream>>>(W1, b1, W2, b2, ei, Bsw1, Bsw2, b1c, b2c, flags);
    hipMemsetAsync(bcnt, 0, (size_t)MAXB * 4, stream);

    k_edges<<<EBLK, 256, 0, stream>>>(ei, E, N, NB, flags, bcnt, ppack);
    k_bsort<<<NB, 512, 0, stream>>>(bcnt, ppack, NB, csr, offsets, dinv, N,
                                    x, flags, xs);

    const int aggGrid = (Npad / 64) * 4;      // 3128: (nb over Npad/64) x 4 slices
    k_agg1<<<aggGrid, 256, 0, stream>>>((const s16x8*)xs, offsets, csr, dinv,
                                        (s16x8*)a1, N, Npad);

    k_gemm12<<<NB, 256, 0, stream>>>(a1, (const __hip_bfloat16*)Bsw1, b1c,
                                     (const __hip_bfloat16*)Bsw2, dinv, h2s);

    k_agg2<<<aggGrid, 256, 0, stream>>>((const s16x8*)h2s, offsets, csr, dinv,
                                        b2c, flags, d_out, N, Npad);
}

// Round 10
// 217.395 us; speedup vs baseline: 1.0633x; 1.0633x over previous
//
#include <hip/hip_runtime.h>
#include <hip/hip_bf16.h>

// GCN 2-layer encoder, MI355X (gfx950).
// Known: float tensors bf16, edge_index int64 (self-detection kept).
// Round 10: revert XCD-slicing (R9 post-mortem: bid%8->XCD affinity false,
// FETCH 84->125MB); aggs back to R8 grouped gather (16 lanes/row, 4 groups,
// unroll4 — the 44.5us/84MB operating point). prep_w fused into k_edges
// (k_pe, block-role split). 6 dispatches.
// Pipeline:
//   memset bcnt -> k_pe (edges bucketing + weight prep + flags)
//   k_bsort(+scan +prescale xs=dinv*x): CSR/offsets/dinv/xs
//   a1[v] = dinv[v]*(xs[v] + sum xs[csr])      [grouped gather]
//   h2s = (relu(a1@W1+b1) @ W2) * dinv[row]     [fused MFMA, LDS h1]
//   out[v] = dinv[v]*(h2s[v] + sum h2s[csr]) + b2   [grouped gather]

typedef __bf16 bf16x8v __attribute__((ext_vector_type(8)));
typedef short  s16x8   __attribute__((ext_vector_type(8)));
typedef float  f32x4   __attribute__((ext_vector_type(4)));

#define IN_DIM 128
#define HID    256
#define OUTD   128
#define BKT_SHIFT 7
#define BKT_NODES 128
#define MAXB 512            // max buckets (N <= 65536)
#define CAP  8192           // per-bucket capacity (mean 2046, 40+ sigma margin)
#define EBLK 512            // edge-bucketing blocks in k_pe

__device__ __forceinline__ float2 bf2f(__hip_bfloat162 v) {
    return make_float2(__bfloat162float(v.x), __bfloat162float(v.y));
}
__device__ __forceinline__ __hip_bfloat162 f2bf(float a, float b) {
    __hip_bfloat162 r; r.x = __float2bfloat16(a); r.y = __float2bfloat16(b); return r;
}
__device__ __forceinline__ void acc_row(float* acc, s16x8 r) {
    __hip_bfloat162* p = (__hip_bfloat162*)&r;
#pragma unroll
    for (int j = 0; j < 4; ++j) {
        float2 f = bf2f(p[j]);
        acc[2 * j]     += f.x;
        acc[2 * j + 1] += f.y;
    }
}

// dtype self-detection (W2 uniform +-1/16: any bf16-exp >= 0x7F => fp32)
__device__ __forceinline__ int detect_f32(const void* W2raw) {
    const unsigned short* u = (const unsigned short*)W2raw;
    int f32 = 0;
#pragma unroll
    for (int i = 0; i < 64; ++i) {
        unsigned e = (u[i] >> 7) & 0xFF;
        if (e >= 0x7F) f32 = 1;
    }
    return f32;
}
__device__ __forceinline__ int detect_i64(const void* eiraw) {
    const unsigned* ip = (const unsigned*)eiraw;
    unsigned orodd = 0;
#pragma unroll
    for (int i = 0; i < 64; ++i) orodd |= ip[2 * i + 1];
    return (orodd == 0) ? 1 : 0;
}

__device__ __forceinline__ short ldw(const void* raw, int idx, int f32) {
    if (f32) {
        __hip_bfloat16 h = __float2bfloat16(((const float*)raw)[idx]);
        return *(short*)&h;
    }
    return ((const short*)raw)[idx];
}

template <int K, int NN>
__device__ __forceinline__ void swz_one(const void* Wraw, int f32,
                                        short* __restrict__ Bsw, int tid) {
    constexpr int KC = K / 32;
    constexpr int NT = NN / 16;
    if (tid >= NT * KC * 64) return;
    int lane = tid & 63;
    int kc   = (tid >> 6) % KC;
    int nt   = tid / (64 * KC);
    int n  = nt * 16 + (lane & 15);
    int kb = kc * 32 + (lane >> 4) * 8;
    s16x8 v;
#pragma unroll
    for (int j = 0; j < 8; ++j) v[j] = ldw(Wraw, (kb + j) * NN + n, f32);
    ((s16x8*)Bsw)[tid] = v;
}

// ---------------- fused: edge bucketing + weight prep + flags ----------------
// blocks [0,EBLK): edge pass (wave-privatized LDS hist, packed scatter)
// blocks [EBLK, EBLK+16): W1 swizzle; [EBLK+16, EBLK+32): W2; EBLK+32: biases+flags

__global__ __launch_bounds__(256) void k_pe(
        const void* __restrict__ ei_, int E, int N, int NB,
        int* __restrict__ bcnt, unsigned* __restrict__ ppack,
        const void* W1raw, const void* b1raw, const void* W2raw, const void* b2raw,
        short* __restrict__ Bsw1, short* __restrict__ Bsw2,
        __hip_bfloat16* __restrict__ b1c, __hip_bfloat16* __restrict__ b2c,
        int* __restrict__ flags) {
    int blk = blockIdx.x, t = threadIdx.x;
    if (blk >= EBLK) {
        int f32 = detect_f32(W2raw);
        int pb = blk - EBLK;
        if (pb < 16) {
            swz_one<IN_DIM, HID>(W1raw, f32, Bsw1, pb * 256 + t);
        } else if (pb < 32) {
            swz_one<HID, OUTD>(W2raw, f32, Bsw2, (pb - 16) * 256 + t);
        } else {
            short s1 = ldw(b1raw, t, f32);
            b1c[t] = *(__hip_bfloat16*)&s1;
            if (t < OUTD) {
                short s2 = ldw(b2raw, t, f32);
                b2c[t] = *(__hip_bfloat16*)&s2;
            }
            if (t == 0) {
                flags[0] = f32;
                flags[1] = detect_i64(ei_);
            }
        }
        return;
    }
    // edge pass
    __shared__ int lhist[4][MAXB];
    __shared__ int lbase[4][MAXB];
    int wv = t >> 6;
    int i64 = detect_i64(ei_);
    const long long* p64 = (const long long*)ei_;
    const int*       p32 = (const int*)ei_;
    int per = (E + EBLK - 1) / EBLK;
    int e0 = blk * per, e1 = min(e0 + per, E);
    for (int i = t; i < NB; i += 256) {
        lhist[0][i] = 0; lhist[1][i] = 0; lhist[2][i] = 0; lhist[3][i] = 0;
    }
    __syncthreads();
    for (int e = e0 + t; e < e1; e += 256) {
        int d = i64 ? (int)p64[E + e] : p32[E + e];
        if ((unsigned)d >= (unsigned)N) d = 0;
        atomicAdd(&lhist[wv][((unsigned)d) >> BKT_SHIFT], 1);
    }
    __syncthreads();
    for (int i = t; i < NB; i += 256) {
        int c0 = lhist[0][i], c1 = lhist[1][i], c2 = lhist[2][i], c3 = lhist[3][i];
        int tot = c0 + c1 + c2 + c3;
        int g = tot ? atomicAdd(&bcnt[i], tot) : 0;
        lbase[0][i] = g;
        lbase[1][i] = g + c0;
        lbase[2][i] = g + c0 + c1;
        lbase[3][i] = g + c0 + c1 + c2;
        lhist[0][i] = 0; lhist[1][i] = 0; lhist[2][i] = 0; lhist[3][i] = 0;
    }
    __syncthreads();
    for (int e = e0 + t; e < e1; e += 256) {
        int d = i64 ? (int)p64[E + e] : p32[E + e];
        int s = i64 ? (int)p64[e]     : p32[e];
        if ((unsigned)d >= (unsigned)N) d = 0;
        if ((unsigned)s >= (unsigned)N) s = 0;
        int b = ((unsigned)d) >> BKT_SHIFT;
        int pos = lbase[wv][b] + atomicAdd(&lhist[wv][b], 1);
        if (pos < CAP)
            ppack[(size_t)b * CAP + pos] = ((unsigned)(d & (BKT_NODES - 1)) << 25) | (unsigned)s;
    }
}

// ---------------- bucket sort (+bucket scan, +prescale xs) ----------------

__global__ __launch_bounds__(512) void k_bsort(const int* __restrict__ bcnt,
                                               const unsigned* __restrict__ ppack,
                                               int NB,
                                               int* __restrict__ csr, int* __restrict__ offsets,
                                               float* __restrict__ dinv, int N,
                                               const void* __restrict__ xraw,
                                               const int* __restrict__ flags,
                                               __hip_bfloat16* __restrict__ xs) {
    __shared__ int sb[MAXB];
    __shared__ int h[BKT_NODES], base[BKT_NODES], s[BKT_NODES];
    __shared__ float sdv[BKT_NODES];
    int b = blockIdx.x;
    int t = threadIdx.x;
    int c = (t < NB) ? min(bcnt[t], CAP) : 0;
    sb[t] = c;
    __syncthreads();
    for (int off = 1; off < MAXB; off <<= 1) {
        int u = (t >= off) ? sb[t - off] : 0;
        __syncthreads();
        sb[t] += u;
        __syncthreads();
    }
    int cnt   = min(bcnt[b], CAP);
    int ebase = sb[b] - cnt;
    if (b == NB - 1 && t == 0) offsets[N] = sb[b];
    const unsigned* pp = ppack + (size_t)b * CAP;
    if (t < BKT_NODES) h[t] = 0;
    __syncthreads();
    for (int e = t; e < cnt; e += 512) atomicAdd(&h[pp[e] >> 25], 1);
    __syncthreads();
    int v = (t < BKT_NODES) ? h[t] : 0;
    if (t < BKT_NODES) s[t] = v;
    __syncthreads();
    for (int off = 1; off < BKT_NODES; off <<= 1) {
        int u = (t < BKT_NODES && t >= off) ? s[t - off] : 0;
        __syncthreads();
        if (t < BKT_NODES) s[t] += u;
        __syncthreads();
    }
    if (t < BKT_NODES) {
        int excl = s[t] - v;
        base[t] = excl;
        int node = b * BKT_NODES + t;
        float dv = 0.f;
        if (node < N) {
            dv = rsqrtf((float)(v + 1));
            offsets[node] = ebase + excl;
            dinv[node] = dv;
        } else {
            dinv[node] = 0.f;
        }
        sdv[t] = dv;
        h[t] = 0;
    }
    __syncthreads();
    for (int e = t; e < cnt; e += 512) {
        unsigned pk = pp[e];
        int ld = pk >> 25;
        int pos = ebase + base[ld] + atomicAdd(&h[ld], 1);
        csr[pos] = (int)(pk & 0x1FFFFFFu);
    }
    // fused prescale: xs rows [b*128, b*128+128) = dinv * x
    int f32 = flags[0];
    if (!f32) {
        const s16x8* xg = (const s16x8*)xraw;
        s16x8* xo = (s16x8*)xs;
        for (int u = t; u < BKT_NODES * 16; u += 512) {
            int row = u >> 4;
            int node = b * BKT_NODES + row;
            float dv = sdv[row];
            s16x8 val = {0, 0, 0, 0, 0, 0, 0, 0};
            if (node < N) {
                s16x8 xin = xg[(size_t)node * 16 + (u & 15)];
                __hip_bfloat162* xp = (__hip_bfloat162*)&xin;
                __hip_bfloat162* vp = (__hip_bfloat162*)&val;
#pragma unroll
                for (int j = 0; j < 4; ++j) {
                    float2 f = bf2f(xp[j]);
                    vp[j] = f2bf(dv * f.x, dv * f.y);
                }
            }
            xo[(size_t)node * 16 + (u & 15)] = val;
        }
    } else {
        const float4* xg = (const float4*)xraw;
        __hip_bfloat162* xo = (__hip_bfloat162*)xs;
        for (int u = t; u < BKT_NODES * 32; u += 512) {
            int row = u >> 5;
            int node = b * BKT_NODES + row;
            float dv = sdv[row];
            __hip_bfloat162 v0 = f2bf(0.f, 0.f), v1 = v0;
            if (node < N) {
                float4 xin = xg[(size_t)node * 32 + (u & 31)];
                v0 = f2bf(dv * xin.x, dv * xin.y);
                v1 = f2bf(dv * xin.z, dv * xin.w);
            }
            xo[(size_t)node * 64 + (u & 31) * 2]     = v0;
            xo[(size_t)node * 64 + (u & 31) * 2 + 1] = v1;
        }
    }
}

// ---------------- aggregation 1 (grouped gather, R8 structure) ----------------
// 16 lanes per row (16B/lane), 4 edge-groups per wave, shfl_xor combine.

__global__ __launch_bounds__(256) void k_agg1(
        const s16x8* __restrict__ xs8, const int* __restrict__ offsets,
        const int* __restrict__ csr, const float* __restrict__ dinv,
        s16x8* __restrict__ a8, int N, int Npad, int nwaves) {
    int gw   = blockIdx.x * 4 + (threadIdx.x >> 6);
    int lane = threadIdx.x & 63;
    int g = lane >> 4, li = lane & 15;
    for (int v = gw; v < Npad; v += nwaves) {
        if (v >= N) {
            if (g == 0) { s16x8 z = {0,0,0,0,0,0,0,0}; a8[(size_t)v * 16 + li] = z; }
            continue;
        }
        float acc[8];
#pragma unroll
        for (int j = 0; j < 8; ++j) acc[j] = 0.f;
        int o0 = offsets[v], o1 = offsets[v + 1];
        if (g == 0) acc_row(acc, xs8[(size_t)v * 16 + li]);   // self (pre-scaled)
        int e = o0 + g;
        for (; e + 12 < o1; e += 16) {
            int s0 = csr[e], s1 = csr[e + 4], s2 = csr[e + 8], s3 = csr[e + 12];
            s16x8 r0 = xs8[(size_t)s0 * 16 + li];
            s16x8 r1 = xs8[(size_t)s1 * 16 + li];
            s16x8 r2 = xs8[(size_t)s2 * 16 + li];
            s16x8 r3 = xs8[(size_t)s3 * 16 + li];
            acc_row(acc, r0); acc_row(acc, r1); acc_row(acc, r2); acc_row(acc, r3);
        }
        for (; e < o1; e += 4) acc_row(acc, xs8[(size_t)csr[e] * 16 + li]);
#pragma unroll
        for (int j = 0; j < 8; ++j) {
            acc[j] += __shfl_xor(acc[j], 16, 64);
            acc[j] += __shfl_xor(acc[j], 32, 64);
        }
        if (g == 0) {
            float dv = dinv[v];
            s16x8 outv;
            __hip_bfloat162* op = (__hip_bfloat162*)&outv;
#pragma unroll
            for (int j = 0; j < 4; ++j) op[j] = f2bf(dv * acc[2 * j], dv * acc[2 * j + 1]);
            a8[(size_t)v * 16 + li] = outv;
        }
    }
}

// ---------------- fused MFMA GEMM1+GEMM2 ----------------

__global__ __launch_bounds__(256) void k_gemm12(
        const __hip_bfloat16* __restrict__ A, const __hip_bfloat16* __restrict__ Bsw1,
        const __hip_bfloat16* __restrict__ b1c, const __hip_bfloat16* __restrict__ Bsw2,
        const float* __restrict__ dinv, __hip_bfloat16* __restrict__ h2s) {
    __shared__ __align__(16) __hip_bfloat16 hl[128 * HID];   // 64 KB
    int wave = threadIdx.x >> 6, lane = threadIdx.x & 63;
    int quad = lane >> 4, l16 = lane & 15;
    int mw = wave * 32;
    int gm = blockIdx.x * 128 + mw;

    bf16x8v a1f[2][4];
#pragma unroll
    for (int st = 0; st < 2; ++st)
#pragma unroll
        for (int kc = 0; kc < 4; ++kc)
            a1f[st][kc] = *reinterpret_cast<const bf16x8v*>(
                A + (size_t)(gm + st * 16 + l16) * IN_DIM + kc * 32 + quad * 8);

    const bf16x8v* B1 = reinterpret_cast<const bf16x8v*>(Bsw1);
    for (int nt = 0; nt < HID / 16; ++nt) {
        f32x4 acc0 = {0.f, 0.f, 0.f, 0.f}, acc1 = {0.f, 0.f, 0.f, 0.f};
#pragma unroll
        for (int kc = 0; kc < 4; ++kc) {
            bf16x8v bfrag = B1[(nt * 4 + kc) * 64 + lane];
            acc0 = __builtin_amdgcn_mfma_f32_16x16x32_bf16(a1f[0][kc], bfrag, acc0, 0, 0, 0);
            acc1 = __builtin_amdgcn_mfma_f32_16x16x32_bf16(a1f[1][kc], bfrag, acc1, 0, 0, 0);
        }
        int col = nt * 16 + l16;
        int gcol = col >> 3, csub = col & 7;
        float bv = __bfloat162float(b1c[col]);
#pragma unroll
        for (int r = 0; r < 4; ++r) {
            float v0 = acc0[r] + bv; v0 = v0 > 0.f ? v0 : 0.f;
            float v1 = acc1[r] + bv; v1 = v1 > 0.f ? v1 : 0.f;
            int r0 = mw + quad * 4 + r;
            int r1 = mw + 16 + quad * 4 + r;
            ((__hip_bfloat16*)((char*)hl + (size_t)r0 * (HID * 2) + ((gcol ^ (r0 & 31)) << 4)))[csub] = __float2bfloat16(v0);
            ((__hip_bfloat16*)((char*)hl + (size_t)r1 * (HID * 2) + ((gcol ^ (r1 & 31)) << 4)))[csub] = __float2bfloat16(v1);
        }
    }
    // per-wave-private rows: no __syncthreads needed

    bf16x8v a2f[2][8];
#pragma unroll
    for (int st = 0; st < 2; ++st)
#pragma unroll
        for (int kc = 0; kc < 8; ++kc) {
            int row = mw + st * 16 + l16;
            int g = (kc * 4 + quad) ^ (row & 31);
            a2f[st][kc] = *reinterpret_cast<const bf16x8v*>(
                (char*)hl + (size_t)row * (HID * 2) + ((size_t)g << 4));
        }
    const bf16x8v* B2 = reinterpret_cast<const bf16x8v*>(Bsw2);
    int rb0 = gm + quad * 4, rb1 = gm + 16 + quad * 4;
    float sc0[4], sc1[4];
#pragma unroll
    for (int r = 0; r < 4; ++r) { sc0[r] = dinv[rb0 + r]; sc1[r] = dinv[rb1 + r]; }
    for (int nt = 0; nt < OUTD / 16; ++nt) {
        f32x4 acc0 = {0.f, 0.f, 0.f, 0.f}, acc1 = {0.f, 0.f, 0.f, 0.f};
#pragma unroll
        for (int kc = 0; kc < 8; ++kc) {
            bf16x8v bfrag = B2[(nt * 8 + kc) * 64 + lane];
            acc0 = __builtin_amdgcn_mfma_f32_16x16x32_bf16(a2f[0][kc], bfrag, acc0, 0, 0, 0);
            acc1 = __builtin_amdgcn_mfma_f32_16x16x32_bf16(a2f[1][kc], bfrag, acc1, 0, 0, 0);
        }
        int col = nt * 16 + l16;
#pragma unroll
        for (int r = 0; r < 4; ++r) {
            h2s[(size_t)(rb0 + r) * OUTD + col] = __float2bfloat16(acc0[r] * sc0[r]);
            h2s[(size_t)(rb1 + r) * OUTD + col] = __float2bfloat16(acc1[r] * sc1[r]);
        }
    }
}

// ---------------- aggregation 2 (grouped gather, R8 structure) ----------------

__global__ __launch_bounds__(256) void k_agg2(
        const s16x8* __restrict__ h8, const int* __restrict__ offsets,
        const int* __restrict__ csr, const float* __restrict__ dinv,
        const __hip_bfloat16* __restrict__ b2c, const int* __restrict__ flags,
        void* __restrict__ outraw, int N, int nwaves) {
    int gw   = blockIdx.x * 4 + (threadIdx.x >> 6);
    int lane = threadIdx.x & 63;
    int g = lane >> 4, li = lane & 15;
    int f32 = flags[0];
    float bb[8];
    {
        s16x8 bv = ((const s16x8*)b2c)[li];
        __hip_bfloat162* bp = (__hip_bfloat162*)&bv;
#pragma unroll
        for (int j = 0; j < 4; ++j) {
            float2 f = bf2f(bp[j]);
            bb[2 * j] = f.x; bb[2 * j + 1] = f.y;
        }
    }
    for (int v = gw; v < N; v += nwaves) {
        float acc[8];
#pragma unroll
        for (int j = 0; j < 8; ++j) acc[j] = 0.f;
        int o0 = offsets[v], o1 = offsets[v + 1];
        if (g == 0) acc_row(acc, h8[(size_t)v * 16 + li]);    // self (pre-scaled)
        int e = o0 + g;
        for (; e + 12 < o1; e += 16) {
            int s0 = csr[e], s1 = csr[e + 4], s2 = csr[e + 8], s3 = csr[e + 12];
            s16x8 r0 = h8[(size_t)s0 * 16 + li];
            s16x8 r1 = h8[(size_t)s1 * 16 + li];
            s16x8 r2 = h8[(size_t)s2 * 16 + li];
            s16x8 r3 = h8[(size_t)s3 * 16 + li];
            acc_row(acc, r0); acc_row(acc, r1); acc_row(acc, r2); acc_row(acc, r3);
        }
        for (; e < o1; e += 4) acc_row(acc, h8[(size_t)csr[e] * 16 + li]);
#pragma unroll
        for (int j = 0; j < 8; ++j) {
            acc[j] += __shfl_xor(acc[j], 16, 64);
            acc[j] += __shfl_xor(acc[j], 32, 64);
        }
        if (g == 0) {
            float dv = dinv[v];
            if (f32) {
                float4* of = (float4*)outraw;
                float4 o0v = {dv * acc[0] + bb[0], dv * acc[1] + bb[1],
                              dv * acc[2] + bb[2], dv * acc[3] + bb[3]};
                float4 o1v = {dv * acc[4] + bb[4], dv * acc[5] + bb[5],
                              dv * acc[6] + bb[6], dv * acc[7] + bb[7]};
                of[(size_t)v * 32 + li * 2]     = o0v;
                of[(size_t)v * 32 + li * 2 + 1] = o1v;
            } else {
                s16x8 outv;
                __hip_bfloat162* op = (__hip_bfloat162*)&outv;
#pragma unroll
                for (int j = 0; j < 4; ++j)
                    op[j] = f2bf(dv * acc[2 * j] + bb[2 * j], dv * acc[2 * j + 1] + bb[2 * j + 1]);
                ((s16x8*)outraw)[(size_t)v * 16 + li] = outv;
            }
        }
    }
}

// ---------------- host launch ----------------

extern "C" void kernel_launch(void* const* d_in, const int* in_sizes, int n_in,
                              void* d_out, int out_size, void* d_ws, size_t ws_size,
                              hipStream_t stream) {
    const void* x  = d_in[0];
    const void* ei = d_in[1];
    const void* W1 = d_in[2];
    const void* b1 = d_in[3];
    const void* W2 = d_in[4];
    const void* b2 = d_in[5];

    const int N = in_sizes[0] / IN_DIM;       // 50000
    const int E = in_sizes[1] / 2;            // 800000
    const int Npad = ((N + 127) / 128) * 128; // 50048 (multiple of 128)
    const int NB = Npad / BKT_NODES;          // 391

    char* w = (char*)d_ws;
    auto alloc = [&](size_t bytes) -> void* {
        void* p = (void*)w;
        w += (bytes + 255) / 256 * 256;
        return p;
    };
    int*   flags   = (int*)alloc(256);
    int*   bcnt    = (int*)alloc((size_t)MAXB * 4);
    int*   offsets = (int*)alloc((size_t)(N + 1) * 4);
    float* dinv    = (float*)alloc((size_t)Npad * 4);
    unsigned* ppack = (unsigned*)alloc((size_t)NB * CAP * 4);
    int*   csr     = (int*)alloc((size_t)E * 4);
    short* Bsw1 = (short*)alloc((size_t)IN_DIM * HID * 2);
    short* Bsw2 = (short*)alloc((size_t)HID * OUTD * 2);
    __hip_bfloat16* b1c = (__hip_bfloat16*)alloc((size_t)HID * 2);
    __hip_bfloat16* b2c = (__hip_bfloat16*)alloc((size_t)OUTD * 2);
    __hip_bfloat16* xs  = (__hip_bfloat16*)alloc((size_t)Npad * IN_DIM * 2);
    __hip_bfloat16* a1  = (__hip_bfloat16*)alloc((size_t)Npad * IN_DIM * 2);
    __hip_bfloat16* h2s = xs;   // xs dead after agg1; reuse for gemm12 output

    hipMemsetAsync(bcnt, 0, (size_t)MAXB * 4, stream);

    k_pe<<<EBLK + 33, 256, 0, stream>>>(ei, E, N, NB, bcnt, ppack,
                                        W1, b1, W2, b2, Bsw1, Bsw2, b1c, b2c, flags);

    k_bsort<<<NB, 512, 0, stream>>>(bcnt, ppack, NB, csr, offsets, dinv, N,
                                    x, flags, xs);

    const int aggBlocks = 2048, nwaves = aggBlocks * 4;
    k_agg1<<<aggBlocks, 256, 0, stream>>>((const s16x8*)xs, offsets, csr, dinv,
                                          (s16x8*)a1, N, Npad, nwaves);

    k_gemm12<<<NB, 256, 0, stream>>>(a1, (const __hip_bfloat16*)Bsw1, b1c,
                                     (const __hip_bfloat16*)Bsw2, dinv, h2s);

    k_agg2<<<aggBlocks, 256, 0, stream>>>((const s16x8*)h2s, offsets, csr, dinv,
                                          b2c, flags, d_out, N, nwaves);
}

// Round 11
// 213.874 us; speedup vs baseline: 1.0808x; 1.0165x over previous
//
#include <hip/hip_runtime.h>
#include <hip/hip_bf16.h>

// GCN 2-layer encoder, MI355X (gfx950).
// Known: float tensors bf16, edge_index int64 (self-detection kept).
// Round 11: gemm12 64-row tiles (782 blocks, 32KB LDS, ~4 blk/CU — was 391
// blocks @64KB leaving CUs idle); agg grids 2048->3072 (shorter tails).
// Gathers at demonstrated random-L2-miss floor (~45us each, 84MB fetch).
// 6 dispatches.
// Pipeline:
//   memset bcnt -> k_pe (edges bucketing + weight prep + flags)
//   k_bsort(+scan +prescale xs=dinv*x): CSR/offsets/dinv/xs
//   a1[v] = dinv[v]*(xs[v] + sum xs[csr])      [grouped gather]
//   h2s = (relu(a1@W1+b1) @ W2) * dinv[row]     [fused MFMA, LDS h1]
//   out[v] = dinv[v]*(h2s[v] + sum h2s[csr]) + b2   [grouped gather]

typedef __bf16 bf16x8v __attribute__((ext_vector_type(8)));
typedef short  s16x8   __attribute__((ext_vector_type(8)));
typedef float  f32x4   __attribute__((ext_vector_type(4)));

#define IN_DIM 128
#define HID    256
#define OUTD   128
#define BKT_SHIFT 7
#define BKT_NODES 128
#define MAXB 512            // max buckets (N <= 65536)
#define CAP  8192           // per-bucket capacity (mean 2046, 40+ sigma margin)
#define EBLK 512            // edge-bucketing blocks in k_pe

__device__ __forceinline__ float2 bf2f(__hip_bfloat162 v) {
    return make_float2(__bfloat162float(v.x), __bfloat162float(v.y));
}
__device__ __forceinline__ __hip_bfloat162 f2bf(float a, float b) {
    __hip_bfloat162 r; r.x = __float2bfloat16(a); r.y = __float2bfloat16(b); return r;
}
__device__ __forceinline__ void acc_row(float* acc, s16x8 r) {
    __hip_bfloat162* p = (__hip_bfloat162*)&r;
#pragma unroll
    for (int j = 0; j < 4; ++j) {
        float2 f = bf2f(p[j]);
        acc[2 * j]     += f.x;
        acc[2 * j + 1] += f.y;
    }
}

// dtype self-detection (W2 uniform +-1/16: any bf16-exp >= 0x7F => fp32)
__device__ __forceinline__ int detect_f32(const void* W2raw) {
    const unsigned short* u = (const unsigned short*)W2raw;
    int f32 = 0;
#pragma unroll
    for (int i = 0; i < 64; ++i) {
        unsigned e = (u[i] >> 7) & 0xFF;
        if (e >= 0x7F) f32 = 1;
    }
    return f32;
}
__device__ __forceinline__ int detect_i64(const void* eiraw) {
    const unsigned* ip = (const unsigned*)eiraw;
    unsigned orodd = 0;
#pragma unroll
    for (int i = 0; i < 64; ++i) orodd |= ip[2 * i + 1];
    return (orodd == 0) ? 1 : 0;
}

__device__ __forceinline__ short ldw(const void* raw, int idx, int f32) {
    if (f32) {
        __hip_bfloat16 h = __float2bfloat16(((const float*)raw)[idx]);
        return *(short*)&h;
    }
    return ((const short*)raw)[idx];
}

template <int K, int NN>
__device__ __forceinline__ void swz_one(const void* Wraw, int f32,
                                        short* __restrict__ Bsw, int tid) {
    constexpr int KC = K / 32;
    constexpr int NT = NN / 16;
    if (tid >= NT * KC * 64) return;
    int lane = tid & 63;
    int kc   = (tid >> 6) % KC;
    int nt   = tid / (64 * KC);
    int n  = nt * 16 + (lane & 15);
    int kb = kc * 32 + (lane >> 4) * 8;
    s16x8 v;
#pragma unroll
    for (int j = 0; j < 8; ++j) v[j] = ldw(Wraw, (kb + j) * NN + n, f32);
    ((s16x8*)Bsw)[tid] = v;
}

// ---------------- fused: edge bucketing + weight prep + flags ----------------

__global__ __launch_bounds__(256) void k_pe(
        const void* __restrict__ ei_, int E, int N, int NB,
        int* __restrict__ bcnt, unsigned* __restrict__ ppack,
        const void* W1raw, const void* b1raw, const void* W2raw, const void* b2raw,
        short* __restrict__ Bsw1, short* __restrict__ Bsw2,
        __hip_bfloat16* __restrict__ b1c, __hip_bfloat16* __restrict__ b2c,
        int* __restrict__ flags) {
    int blk = blockIdx.x, t = threadIdx.x;
    if (blk >= EBLK) {
        int f32 = detect_f32(W2raw);
        int pb = blk - EBLK;
        if (pb < 16) {
            swz_one<IN_DIM, HID>(W1raw, f32, Bsw1, pb * 256 + t);
        } else if (pb < 32) {
            swz_one<HID, OUTD>(W2raw, f32, Bsw2, (pb - 16) * 256 + t);
        } else {
            short s1 = ldw(b1raw, t, f32);
            b1c[t] = *(__hip_bfloat16*)&s1;
            if (t < OUTD) {
                short s2 = ldw(b2raw, t, f32);
                b2c[t] = *(__hip_bfloat16*)&s2;
            }
            if (t == 0) {
                flags[0] = f32;
                flags[1] = detect_i64(ei_);
            }
        }
        return;
    }
    __shared__ int lhist[4][MAXB];
    __shared__ int lbase[4][MAXB];
    int wv = t >> 6;
    int i64 = detect_i64(ei_);
    const long long* p64 = (const long long*)ei_;
    const int*       p32 = (const int*)ei_;
    int per = (E + EBLK - 1) / EBLK;
    int e0 = blk * per, e1 = min(e0 + per, E);
    for (int i = t; i < NB; i += 256) {
        lhist[0][i] = 0; lhist[1][i] = 0; lhist[2][i] = 0; lhist[3][i] = 0;
    }
    __syncthreads();
    for (int e = e0 + t; e < e1; e += 256) {
        int d = i64 ? (int)p64[E + e] : p32[E + e];
        if ((unsigned)d >= (unsigned)N) d = 0;
        atomicAdd(&lhist[wv][((unsigned)d) >> BKT_SHIFT], 1);
    }
    __syncthreads();
    for (int i = t; i < NB; i += 256) {
        int c0 = lhist[0][i], c1 = lhist[1][i], c2 = lhist[2][i], c3 = lhist[3][i];
        int tot = c0 + c1 + c2 + c3;
        int g = tot ? atomicAdd(&bcnt[i], tot) : 0;
        lbase[0][i] = g;
        lbase[1][i] = g + c0;
        lbase[2][i] = g + c0 + c1;
        lbase[3][i] = g + c0 + c1 + c2;
        lhist[0][i] = 0; lhist[1][i] = 0; lhist[2][i] = 0; lhist[3][i] = 0;
    }
    __syncthreads();
    for (int e = e0 + t; e < e1; e += 256) {
        int d = i64 ? (int)p64[E + e] : p32[E + e];
        int s = i64 ? (int)p64[e]     : p32[e];
        if ((unsigned)d >= (unsigned)N) d = 0;
        if ((unsigned)s >= (unsigned)N) s = 0;
        int b = ((unsigned)d) >> BKT_SHIFT;
        int pos = lbase[wv][b] + atomicAdd(&lhist[wv][b], 1);
        if (pos < CAP)
            ppack[(size_t)b * CAP + pos] = ((unsigned)(d & (BKT_NODES - 1)) << 25) | (unsigned)s;
    }
}

// ---------------- bucket sort (+bucket scan, +prescale xs) ----------------

__global__ __launch_bounds__(512) void k_bsort(const int* __restrict__ bcnt,
                                               const unsigned* __restrict__ ppack,
                                               int NB,
                                               int* __restrict__ csr, int* __restrict__ offsets,
                                               float* __restrict__ dinv, int N,
                                               const void* __restrict__ xraw,
                                               const int* __restrict__ flags,
                                               __hip_bfloat16* __restrict__ xs) {
    __shared__ int sb[MAXB];
    __shared__ int h[BKT_NODES], base[BKT_NODES], s[BKT_NODES];
    __shared__ float sdv[BKT_NODES];
    int b = blockIdx.x;
    int t = threadIdx.x;
    int c = (t < NB) ? min(bcnt[t], CAP) : 0;
    sb[t] = c;
    __syncthreads();
    for (int off = 1; off < MAXB; off <<= 1) {
        int u = (t >= off) ? sb[t - off] : 0;
        __syncthreads();
        sb[t] += u;
        __syncthreads();
    }
    int cnt   = min(bcnt[b], CAP);
    int ebase = sb[b] - cnt;
    if (b == NB - 1 && t == 0) offsets[N] = sb[b];
    const unsigned* pp = ppack + (size_t)b * CAP;
    if (t < BKT_NODES) h[t] = 0;
    __syncthreads();
    for (int e = t; e < cnt; e += 512) atomicAdd(&h[pp[e] >> 25], 1);
    __syncthreads();
    int v = (t < BKT_NODES) ? h[t] : 0;
    if (t < BKT_NODES) s[t] = v;
    __syncthreads();
    for (int off = 1; off < BKT_NODES; off <<= 1) {
        int u = (t < BKT_NODES && t >= off) ? s[t - off] : 0;
        __syncthreads();
        if (t < BKT_NODES) s[t] += u;
        __syncthreads();
    }
    if (t < BKT_NODES) {
        int excl = s[t] - v;
        base[t] = excl;
        int node = b * BKT_NODES + t;
        float dv = 0.f;
        if (node < N) {
            dv = rsqrtf((float)(v + 1));
            offsets[node] = ebase + excl;
            dinv[node] = dv;
        } else {
            dinv[node] = 0.f;
        }
        sdv[t] = dv;
        h[t] = 0;
    }
    __syncthreads();
    for (int e = t; e < cnt; e += 512) {
        unsigned pk = pp[e];
        int ld = pk >> 25;
        int pos = ebase + base[ld] + atomicAdd(&h[ld], 1);
        csr[pos] = (int)(pk & 0x1FFFFFFu);
    }
    // fused prescale: xs rows [b*128, b*128+128) = dinv * x
    int f32 = flags[0];
    if (!f32) {
        const s16x8* xg = (const s16x8*)xraw;
        s16x8* xo = (s16x8*)xs;
        for (int u = t; u < BKT_NODES * 16; u += 512) {
            int row = u >> 4;
            int node = b * BKT_NODES + row;
            float dv = sdv[row];
            s16x8 val = {0, 0, 0, 0, 0, 0, 0, 0};
            if (node < N) {
                s16x8 xin = xg[(size_t)node * 16 + (u & 15)];
                __hip_bfloat162* xp = (__hip_bfloat162*)&xin;
                __hip_bfloat162* vp = (__hip_bfloat162*)&val;
#pragma unroll
                for (int j = 0; j < 4; ++j) {
                    float2 f = bf2f(xp[j]);
                    vp[j] = f2bf(dv * f.x, dv * f.y);
                }
            }
            xo[(size_t)node * 16 + (u & 15)] = val;
        }
    } else {
        const float4* xg = (const float4*)xraw;
        __hip_bfloat162* xo = (__hip_bfloat162*)xs;
        for (int u = t; u < BKT_NODES * 32; u += 512) {
            int row = u >> 5;
            int node = b * BKT_NODES + row;
            float dv = sdv[row];
            __hip_bfloat162 v0 = f2bf(0.f, 0.f), v1 = v0;
            if (node < N) {
                float4 xin = xg[(size_t)node * 32 + (u & 31)];
                v0 = f2bf(dv * xin.x, dv * xin.y);
                v1 = f2bf(dv * xin.z, dv * xin.w);
            }
            xo[(size_t)node * 64 + (u & 31) * 2]     = v0;
            xo[(size_t)node * 64 + (u & 31) * 2 + 1] = v1;
        }
    }
}

// ---------------- aggregation 1 (grouped gather) ----------------
// 16 lanes per row (16B/lane), 4 edge-groups per wave, shfl_xor combine.

__global__ __launch_bounds__(256) void k_agg1(
        const s16x8* __restrict__ xs8, const int* __restrict__ offsets,
        const int* __restrict__ csr, const float* __restrict__ dinv,
        s16x8* __restrict__ a8, int N, int Npad, int nwaves) {
    int gw   = blockIdx.x * 4 + (threadIdx.x >> 6);
    int lane = threadIdx.x & 63;
    int g = lane >> 4, li = lane & 15;
    for (int v = gw; v < Npad; v += nwaves) {
        if (v >= N) {
            if (g == 0) { s16x8 z = {0,0,0,0,0,0,0,0}; a8[(size_t)v * 16 + li] = z; }
            continue;
        }
        float acc[8];
#pragma unroll
        for (int j = 0; j < 8; ++j) acc[j] = 0.f;
        int o0 = offsets[v], o1 = offsets[v + 1];
        if (g == 0) acc_row(acc, xs8[(size_t)v * 16 + li]);   // self (pre-scaled)
        int e = o0 + g;
        for (; e + 12 < o1; e += 16) {
            int s0 = csr[e], s1 = csr[e + 4], s2 = csr[e + 8], s3 = csr[e + 12];
            s16x8 r0 = xs8[(size_t)s0 * 16 + li];
            s16x8 r1 = xs8[(size_t)s1 * 16 + li];
            s16x8 r2 = xs8[(size_t)s2 * 16 + li];
            s16x8 r3 = xs8[(size_t)s3 * 16 + li];
            acc_row(acc, r0); acc_row(acc, r1); acc_row(acc, r2); acc_row(acc, r3);
        }
        for (; e < o1; e += 4) acc_row(acc, xs8[(size_t)csr[e] * 16 + li]);
#pragma unroll
        for (int j = 0; j < 8; ++j) {
            acc[j] += __shfl_xor(acc[j], 16, 64);
            acc[j] += __shfl_xor(acc[j], 32, 64);
        }
        if (g == 0) {
            float dv = dinv[v];
            s16x8 outv;
            __hip_bfloat162* op = (__hip_bfloat162*)&outv;
#pragma unroll
            for (int j = 0; j < 4; ++j) op[j] = f2bf(dv * acc[2 * j], dv * acc[2 * j + 1]);
            a8[(size_t)v * 16 + li] = outv;
        }
    }
}

// ---------------- fused MFMA GEMM1+GEMM2 (64-row tiles) ----------------
// Block = 4 waves, 64 rows/tile, wave owns 16 rows. Phase 1: h1 = relu(A@W1+b1)
// into XOR-swizzled LDS (per-wave-private rows, no barrier). Phase 2:
// h2s = (h1@W2)*dinv. LDS granule swizzle: g = gcol ^ (row&31), 16B granules.

__global__ __launch_bounds__(256) void k_gemm12(
        const __hip_bfloat16* __restrict__ A, const __hip_bfloat16* __restrict__ Bsw1,
        const __hip_bfloat16* __restrict__ b1c, const __hip_bfloat16* __restrict__ Bsw2,
        const float* __restrict__ dinv, __hip_bfloat16* __restrict__ h2s) {
    __shared__ __align__(16) __hip_bfloat16 hl[64 * HID];   // 32 KB
    int wave = threadIdx.x >> 6, lane = threadIdx.x & 63;
    int quad = lane >> 4, l16 = lane & 15;
    int mw = wave * 16;                    // wave row base in tile
    int gm = blockIdx.x * 64 + mw;         // global row base

    // phase 1
    bf16x8v a1f[4];
#pragma unroll
    for (int kc = 0; kc < 4; ++kc)
        a1f[kc] = *reinterpret_cast<const bf16x8v*>(
            A + (size_t)(gm + l16) * IN_DIM + kc * 32 + quad * 8);

    const bf16x8v* B1 = reinterpret_cast<const bf16x8v*>(Bsw1);
    for (int nt = 0; nt < HID / 16; ++nt) {
        f32x4 acc = {0.f, 0.f, 0.f, 0.f};
#pragma unroll
        for (int kc = 0; kc < 4; ++kc)
            acc = __builtin_amdgcn_mfma_f32_16x16x32_bf16(a1f[kc], B1[(nt * 4 + kc) * 64 + lane], acc, 0, 0, 0);
        int col = nt * 16 + l16;
        int gcol = col >> 3, csub = col & 7;
        float bv = __bfloat162float(b1c[col]);
#pragma unroll
        for (int r = 0; r < 4; ++r) {
            float v0 = acc[r] + bv; v0 = v0 > 0.f ? v0 : 0.f;
            int r0 = mw + quad * 4 + r;
            ((__hip_bfloat16*)((char*)hl + (size_t)r0 * (HID * 2) + ((gcol ^ (r0 & 31)) << 4)))[csub] = __float2bfloat16(v0);
        }
    }
    // per-wave-private rows: no __syncthreads needed

    // phase 2
    bf16x8v a2f[8];
#pragma unroll
    for (int kc = 0; kc < 8; ++kc) {
        int row = mw + l16;
        int g = (kc * 4 + quad) ^ (row & 31);
        a2f[kc] = *reinterpret_cast<const bf16x8v*>(
            (char*)hl + (size_t)row * (HID * 2) + ((size_t)g << 4));
    }
    const bf16x8v* B2 = reinterpret_cast<const bf16x8v*>(Bsw2);
    int rb0 = gm + quad * 4;
    float sc0[4];
#pragma unroll
    for (int r = 0; r < 4; ++r) sc0[r] = dinv[rb0 + r];
    for (int nt = 0; nt < OUTD / 16; ++nt) {
        f32x4 acc = {0.f, 0.f, 0.f, 0.f};
#pragma unroll
        for (int kc = 0; kc < 8; ++kc)
            acc = __builtin_amdgcn_mfma_f32_16x16x32_bf16(a2f[kc], B2[(nt * 8 + kc) * 64 + lane], acc, 0, 0, 0);
        int col = nt * 16 + l16;
#pragma unroll
        for (int r = 0; r < 4; ++r)
            h2s[(size_t)(rb0 + r) * OUTD + col] = __float2bfloat16(acc[r] * sc0[r]);
    }
}

// ---------------- aggregation 2 (grouped gather) ----------------

__global__ __launch_bounds__(256) void k_agg2(
        const s16x8* __restrict__ h8, const int* __restrict__ offsets,
        const int* __restrict__ csr, const float* __restrict__ dinv,
        const __hip_bfloat16* __restrict__ b2c, const int* __restrict__ flags,
        void* __restrict__ outraw, int N, int nwaves) {
    int gw   = blockIdx.x * 4 + (threadIdx.x >> 6);
    int lane = threadIdx.x & 63;
    int g = lane >> 4, li = lane & 15;
    int f32 = flags[0];
    float bb[8];
    {
        s16x8 bv = ((const s16x8*)b2c)[li];
        __hip_bfloat162* bp = (__hip_bfloat162*)&bv;
#pragma unroll
        for (int j = 0; j < 4; ++j) {
            float2 f = bf2f(bp[j]);
            bb[2 * j] = f.x; bb[2 * j + 1] = f.y;
        }
    }
    for (int v = gw; v < N; v += nwaves) {
        float acc[8];
#pragma unroll
        for (int j = 0; j < 8; ++j) acc[j] = 0.f;
        int o0 = offsets[v], o1 = offsets[v + 1];
        if (g == 0) acc_row(acc, h8[(size_t)v * 16 + li]);    // self (pre-scaled)
        int e = o0 + g;
        for (; e + 12 < o1; e += 16) {
            int s0 = csr[e], s1 = csr[e + 4], s2 = csr[e + 8], s3 = csr[e + 12];
            s16x8 r0 = h8[(size_t)s0 * 16 + li];
            s16x8 r1 = h8[(size_t)s1 * 16 + li];
            s16x8 r2 = h8[(size_t)s2 * 16 + li];
            s16x8 r3 = h8[(size_t)s3 * 16 + li];
            acc_row(acc, r0); acc_row(acc, r1); acc_row(acc, r2); acc_row(acc, r3);
        }
        for (; e < o1; e += 4) acc_row(acc, h8[(size_t)csr[e] * 16 + li]);
#pragma unroll
        for (int j = 0; j < 8; ++j) {
            acc[j] += __shfl_xor(acc[j], 16, 64);
            acc[j] += __shfl_xor(acc[j], 32, 64);
        }
        if (g == 0) {
            float dv = dinv[v];
            if (f32) {
                float4* of = (float4*)outraw;
                float4 o0v = {dv * acc[0] + bb[0], dv * acc[1] + bb[1],
                              dv * acc[2] + bb[2], dv * acc[3] + bb[3]};
                float4 o1v = {dv * acc[4] + bb[4], dv * acc[5] + bb[5],
                              dv * acc[6] + bb[6], dv * acc[7] + bb[7]};
                of[(size_t)v * 32 + li * 2]     = o0v;
                of[(size_t)v * 32 + li * 2 + 1] = o1v;
            } else {
                s16x8 outv;
                __hip_bfloat162* op = (__hip_bfloat162*)&outv;
#pragma unroll
                for (int j = 0; j < 4; ++j)
                    op[j] = f2bf(dv * acc[2 * j] + bb[2 * j], dv * acc[2 * j + 1] + bb[2 * j + 1]);
                ((s16x8*)outraw)[(size_t)v * 16 + li] = outv;
            }
        }
    }
}

// ---------------- host launch ----------------

extern "C" void kernel_launch(void* const* d_in, const int* in_sizes, int n_in,
                              void* d_out, int out_size, void* d_ws, size_t ws_size,
                              hipStream_t stream) {
    const void* x  = d_in[0];
    const void* ei = d_in[1];
    const void* W1 = d_in[2];
    const void* b1 = d_in[3];
    const void* W2 = d_in[4];
    const void* b2 = d_in[5];

    const int N = in_sizes[0] / IN_DIM;       // 50000
    const int E = in_sizes[1] / 2;            // 800000
    const int Npad = ((N + 127) / 128) * 128; // 50048 (multiple of 128)
    const int NB = Npad / BKT_NODES;          // 391

    char* w = (char*)d_ws;
    auto alloc = [&](size_t bytes) -> void* {
        void* p = (void*)w;
        w += (bytes + 255) / 256 * 256;
        return p;
    };
    int*   flags   = (int*)alloc(256);
    int*   bcnt    = (int*)alloc((size_t)MAXB * 4);
    int*   offsets = (int*)alloc((size_t)(N + 1) * 4);
    float* dinv    = (float*)alloc((size_t)Npad * 4);
    unsigned* ppack = (unsigned*)alloc((size_t)NB * CAP * 4);
    int*   csr     = (int*)alloc((size_t)E * 4);
    short* Bsw1 = (short*)alloc((size_t)IN_DIM * HID * 2);
    short* Bsw2 = (short*)alloc((size_t)HID * OUTD * 2);
    __hip_bfloat16* b1c = (__hip_bfloat16*)alloc((size_t)HID * 2);
    __hip_bfloat16* b2c = (__hip_bfloat16*)alloc((size_t)OUTD * 2);
    __hip_bfloat16* xs  = (__hip_bfloat16*)alloc((size_t)Npad * IN_DIM * 2);
    __hip_bfloat16* a1  = (__hip_bfloat16*)alloc((size_t)Npad * IN_DIM * 2);
    __hip_bfloat16* h2s = xs;   // xs dead after agg1; reuse for gemm12 output

    hipMemsetAsync(bcnt, 0, (size_t)MAXB * 4, stream);

    k_pe<<<EBLK + 33, 256, 0, stream>>>(ei, E, N, NB, bcnt, ppack,
                                        W1, b1, W2, b2, Bsw1, Bsw2, b1c, b2c, flags);

    k_bsort<<<NB, 512, 0, stream>>>(bcnt, ppack, NB, csr, offsets, dinv, N,
                                    x, flags, xs);

    const int aggBlocks = 3072, nwaves = aggBlocks * 4;
    k_agg1<<<aggBlocks, 256, 0, stream>>>((const s16x8*)xs, offsets, csr, dinv,
                                          (s16x8*)a1, N, Npad, nwaves);

    k_gemm12<<<Npad / 64, 256, 0, stream>>>(a1, (const __hip_bfloat16*)Bsw1, b1c,
                                            (const __hip_bfloat16*)Bsw2, dinv, h2s);

    k_agg2<<<aggBlocks, 256, 0, stream>>>((const s16x8*)h2s, offsets, csr, dinv,
                                          b2c, flags, d_out, N, nwaves);
}